// Round 4
// baseline (245.469 us; speedup 1.0000x reference)
//
#include <hip/hip_runtime.h>
#include <stdint.h>

typedef __attribute__((ext_vector_type(8))) short short8;
typedef __attribute__((ext_vector_type(4))) float f32x4;
typedef __attribute__((ext_vector_type(2))) float v2f;

#define NCHUNK 32     // 4096 t / 128 t per chunk (2 i-slices per chunk)
#define BROWS  136    // shorts per ldsB row (128 data + 8 pad -> 272 B)
#define XROWD  132    // dwords per ldsX row (128 data + 4 pad -> 528 B)

__device__ __forceinline__ unsigned short f2bf_rne(float f) {
  unsigned u = __builtin_bit_cast(unsigned, f);
  u += 0x7fffu + ((u >> 16) & 1u);
  return (unsigned short)(u >> 16);
}
// pack two f32 -> two bf16 (truncate) in one v_perm_b32; lo short = p0
__device__ __forceinline__ unsigned pack_bf2(float p0, float p1) {
  return __builtin_amdgcn_perm(__builtin_bit_cast(unsigned, p1),
                               __builtin_bit_cast(unsigned, p0), 0x07060302u);
}

// ---- phase 1: M~[k][t] = sum_w wgt[w]*mix[w][k][t] -> bf16, 4-way w-split ----
__global__ __launch_bounds__(256) void prep_kernel(const float* __restrict__ mix,
                                                   const float* __restrict__ wgt,
                                                   unsigned short* __restrict__ Bp) {
  __shared__ float4 red[256];
  const int tid = threadIdx.x;
  const int ws  = tid >> 6;
  const int tt  = tid & 63;
  const int t4  = blockIdx.x * 64 + tt;
  const float4* m4 = (const float4*)mix;
  float ax = 0.f, ay = 0.f, az = 0.f, aw = 0.f;
#pragma unroll
  for (int wi = 0; wi < 8; ++wi) {
    const int w = ws * 8 + wi;
    const float s = wgt[w];
    const float4 v = m4[w * 65536 + t4];
    ax += s * v.x; ay += s * v.y; az += s * v.z; aw += s * v.w;
  }
  red[tid] = (float4){ax, ay, az, aw};
  __syncthreads();
  if (tid < 64) {
    const float4 a = red[tid], b = red[tid + 64], c = red[tid + 128], d = red[tid + 192];
    ushort4 r;
    r.x = f2bf_rne(a.x + b.x + c.x + d.x);
    r.y = f2bf_rne(a.y + b.y + c.y + d.y);
    r.z = f2bf_rne(a.z + b.z + c.z + d.z);
    r.w = f2bf_rne(a.w + b.w + c.w + d.w);
    ((ushort4*)Bp)[blockIdx.x * 64 + tid] = r;
  }
}

// ---- phase 2: out[z][k] = sum_t V[z,t]*M~[k,t], V generated in-register ----
// 128 threads (2 waves); each wave owns 128 z rows (8 MFMA z-frags); block = 256 z.
__global__ __launch_bounds__(128, 1) void gemm_kernel(const float* __restrict__ X,
                                                      const unsigned short* __restrict__ Bp,
                                                      float* __restrict__ out) {
  __shared__ unsigned short ldsB[2][64 * BROWS];  // [buf][k][128-t chunk]
  __shared__ unsigned ldsX[64 * XROWD];           // [i][z-pair dword] bf16

  const int tid  = threadIdx.x;
  const int lane = tid & 63;
  const int wv   = tid >> 6;    // wave 0..1 -> z rows wv*128..+127
  const int m    = lane & 15;
  const int q    = lane >> 4;
  const int zblk = blockIdx.x * 256;

  // ---- stage X^T bf16 into ldsX.
  // dword col(z-pair) = wv*64 + ms*4 + f2 packs z = wv*128 + f2*32 + ms (lo)
  // and z+16 (hi). So lane m's 8 s-values (f=0..7) live at dwords
  // wv*64 + m*4 + {0,1,2,3}: dword f2 -> lo=f(2*f2), hi=f(2*f2+1).
  {
    const float4* X4 = (const float4*)(X + (size_t)zblk * 64);
    const int rr   = tid & 63;
    const int ms   = (rr >> 2) & 15;
    const int f2   = rr & 3;
    const int ze   = wv * 128 + f2 * 32 + ms;   // f = 2*f2
    const int zo   = ze + 16;                   // f = 2*f2+1
    const int dcol = wv * 64 + ms * 4 + f2;
#pragma unroll 4
    for (int c4 = 0; c4 < 16; ++c4) {
      const float4 ve = X4[ze * 16 + c4];
      const float4 vo = X4[zo * 16 + c4];
      float ae[4], ao[4];
      *(float4*)ae = ve; *(float4*)ao = vo;
#pragma unroll
      for (int r = 0; r < 4; ++r) {
        const unsigned pk = (unsigned)f2bf_rne(ae[r]) | ((unsigned)f2bf_rne(ao[r]) << 16);
        ldsX[(c4 * 4 + r) * XROWD + dcol] = pk;
      }
    }
  }
  // ---- stage B chunk 0 into buf 0 ----
  {
#pragma unroll
    for (int it = 0; it < 8; ++it) {
      const int lin = tid + it * 128;  // 0..1023
      const int row = lin >> 4;        // k 0..63
      const int cc  = lin & 15;        // 0..15
      const uint4 v = *(const uint4*)(Bp + row * 4096 + cc * 8);
      *(uint4*)(&ldsB[0][row * BROWS + cc * 8]) = v;
    }
  }

  // ---- per-lane fp32 j-cache: jv2[f][h*4+e] = {x[z(f,m), h*32+q*8+2e], x[.., +1]} ----
  v2f jv2[8][8];
  {
    const float4* X4g = (const float4*)X;
#pragma unroll
    for (int f = 0; f < 8; ++f) {
      const int zg = zblk + wv * 128 + f * 16 + m;
#pragma unroll
      for (int h = 0; h < 2; ++h) {
        const float4 a = X4g[zg * 16 + h * 8 + q * 2];
        const float4 b = X4g[zg * 16 + h * 8 + q * 2 + 1];
        jv2[f][h * 4 + 0] = v2f{a.x, a.y};
        jv2[f][h * 4 + 1] = v2f{a.z, a.w};
        jv2[f][h * 4 + 2] = v2f{b.x, b.y};
        jv2[f][h * 4 + 3] = v2f{b.z, b.w};
      }
    }
  }

  f32x4 acc[8][4];
#pragma unroll
  for (int f = 0; f < 8; ++f)
#pragma unroll
    for (int g = 0; g < 4; ++g) acc[f][g] = f32x4{0.f, 0.f, 0.f, 0.f};

  __syncthreads();

  for (int c = 0; c < NCHUNK; ++c) {
    // prefetch next B chunk global(L2) -> regs; consumed after the MFMA block
    uint4 pre[8];
    const int cn = (c + 1) & (NCHUNK - 1);
#pragma unroll
    for (int it = 0; it < 8; ++it) {
      const int lin = tid + it * 128;
      const int row = lin >> 4;
      const int cc  = lin & 15;
      pre[it] = *(const uint4*)(Bp + row * 4096 + cn * 128 + cc * 8);
    }

    const unsigned short* Bl = ldsB[c & 1];
    const unsigned* xs = ldsX;

#pragma unroll
    for (int il = 0; il < 2; ++il) {
      const int i = c * 2 + il;
      // all 8 s-values (x[z(f,m), i], f=0..7) in one 16B LDS read
      const uint4 sv4 = *(const uint4*)(xs + i * XROWD + wv * 64 + m * 4);
      float sf[8];
      {
        unsigned d[4];
        *(uint4*)d = sv4;
#pragma unroll
        for (int j = 0; j < 4; ++j) {
          sf[2 * j]     = __builtin_bit_cast(float, d[j] << 16);
          sf[2 * j + 1] = __builtin_bit_cast(float, d[j] & 0xffff0000u);
        }
      }
#pragma unroll
      for (int h = 0; h < 2; ++h) {
        const unsigned short* bb = Bl + m * BROWS + il * 64 + h * 32 + q * 8;
        const short8 b0 = *(const short8*)(bb);
        const short8 b1 = *(const short8*)(bb + 16 * BROWS);
        const short8 b2 = *(const short8*)(bb + 32 * BROWS);
        const short8 b3 = *(const short8*)(bb + 48 * BROWS);
#pragma unroll
        for (int f = 0; f < 8; ++f) {
          const v2f s2 = v2f{sf[f], sf[f]};
          union { unsigned u[4]; short8 v; } A;
#pragma unroll
          for (int e = 0; e < 4; ++e) {
            const v2f pr = s2 * jv2[f][h * 4 + e];   // v_pk_mul_f32
            A.u[e] = pack_bf2(pr[0], pr[1]);
          }
          acc[f][0] = __builtin_amdgcn_mfma_f32_16x16x32_bf16(A.v, b0, acc[f][0], 0, 0, 0);
          acc[f][1] = __builtin_amdgcn_mfma_f32_16x16x32_bf16(A.v, b1, acc[f][1], 0, 0, 0);
          acc[f][2] = __builtin_amdgcn_mfma_f32_16x16x32_bf16(A.v, b2, acc[f][2], 0, 0, 0);
          acc[f][3] = __builtin_amdgcn_mfma_f32_16x16x32_bf16(A.v, b3, acc[f][3], 0, 0, 0);
        }
      }
    }

    // publish prefetched chunk into the other buffer
    {
      unsigned short* dst = ldsB[(c + 1) & 1];
#pragma unroll
      for (int it = 0; it < 8; ++it) {
        const int lin = tid + it * 128;
        const int row = lin >> 4;
        const int cc  = lin & 15;
        *(uint4*)(&dst[row * BROWS + cc * 8]) = pre[it];
      }
    }
    __syncthreads();
  }

  // ---- epilogue: C/D layout col=lane&15 (k), row=q*4+r (z) ----
#pragma unroll
  for (int f = 0; f < 8; ++f) {
    const int zr = zblk + wv * 128 + f * 16 + q * 4;
#pragma unroll
    for (int g = 0; g < 4; ++g)
#pragma unroll
      for (int r = 0; r < 4; ++r)
        out[(size_t)(zr + r) * 64 + g * 16 + m] = acc[f][g][r];
  }
}

extern "C" void kernel_launch(void* const* d_in, const int* in_sizes, int n_in,
                              void* d_out, int out_size, void* d_ws, size_t ws_size,
                              hipStream_t stream) {
  const float* X   = (const float*)d_in[0];   // [131072, 64]
  const float* mix = (const float*)d_in[1];   // [32, 64, 64, 64]
  const float* wgt = (const float*)d_in[2];   // [32]
  float* out = (float*)d_out;                 // [131072, 64]
  unsigned short* Bp = (unsigned short*)d_ws; // 512 KB scratch: M~ bf16 [64][4096]

  prep_kernel<<<1024, 256, 0, stream>>>(mix, wgt, Bp);
  gemm_kernel<<<512, 128, 0, stream>>>(X, Bp, out);
}

// Round 5
// 163.575 us; speedup vs baseline: 1.5006x; 1.5006x over previous
//
#include <hip/hip_runtime.h>
#include <stdint.h>

typedef __attribute__((ext_vector_type(8))) short short8;
typedef __attribute__((ext_vector_type(4))) float f32x4;
typedef __attribute__((ext_vector_type(2))) float v2f;

#define NCHUNK 32     // 4096 t / 128 t per chunk (2 i-slices per chunk)
#define BROWS  136    // shorts per ldsB row (128 data + 8 pad -> 272 B)
#define XROWD  130    // dwords per ldsX row (128 z-pair data + 2 pad)

__device__ __forceinline__ unsigned short f2bf_rne(float f) {
  unsigned u = __builtin_bit_cast(unsigned, f);
  u += 0x7fffu + ((u >> 16) & 1u);
  return (unsigned short)(u >> 16);
}
// pack two f32 -> two bf16 (truncate) in one v_perm_b32; lo short = p0
__device__ __forceinline__ unsigned pack_bf2(float p0, float p1) {
  return __builtin_amdgcn_perm(__builtin_bit_cast(unsigned, p1),
                               __builtin_bit_cast(unsigned, p0), 0x07060302u);
}

// ---- phase 1: M~[k][t] = sum_w wgt[w]*mix[w][k][t] -> bf16, 4-way w-split ----
__global__ __launch_bounds__(256) void prep_kernel(const float* __restrict__ mix,
                                                   const float* __restrict__ wgt,
                                                   unsigned short* __restrict__ Bp) {
  __shared__ float4 red[256];
  const int tid = threadIdx.x;
  const int ws  = tid >> 6;
  const int tt  = tid & 63;
  const int t4  = blockIdx.x * 64 + tt;
  const float4* m4 = (const float4*)mix;
  float ax = 0.f, ay = 0.f, az = 0.f, aw = 0.f;
#pragma unroll
  for (int wi = 0; wi < 8; ++wi) {
    const int w = ws * 8 + wi;
    const float s = wgt[w];
    const float4 v = m4[w * 65536 + t4];
    ax += s * v.x; ay += s * v.y; az += s * v.z; aw += s * v.w;
  }
  red[tid] = (float4){ax, ay, az, aw};
  __syncthreads();
  if (tid < 64) {
    const float4 a = red[tid], b = red[tid + 64], c = red[tid + 128], d = red[tid + 192];
    ushort4 r;
    r.x = f2bf_rne(a.x + b.x + c.x + d.x);
    r.y = f2bf_rne(a.y + b.y + c.y + d.y);
    r.z = f2bf_rne(a.z + b.z + c.z + d.z);
    r.w = f2bf_rne(a.w + b.w + c.w + d.w);
    ((ushort4*)Bp)[blockIdx.x * 64 + tid] = r;
  }
}

// ---- phase 2: out[z][k] = sum_t V[z,t]*M~[k,t], V generated in-register ----
// 256 threads (4 waves); each wave owns 64 z rows (F=4 z-frags); block = 256 z.
__global__ __launch_bounds__(256, 2) void gemm_kernel(const float* __restrict__ X,
                                                      const unsigned short* __restrict__ Bp,
                                                      float* __restrict__ out) {
  __shared__ unsigned short ldsB[2][64 * BROWS];  // [buf][k][128-t chunk]   34.8 KB
  __shared__ unsigned ldsX[64 * XROWD];           // [i][z-pair dword] bf16  33.3 KB

  const int tid  = threadIdx.x;
  const int lane = tid & 63;
  const int wv   = tid >> 6;    // wave 0..3 -> z rows wv*64..+63
  const int m    = lane & 15;
  const int q    = lane >> 4;
  const int zblk = blockIdx.x * 256;

  // ---- stage X^T bf16 into ldsX.
  // dword col = wv*32 + m*2 + fd holds z_lo = wv*64 + fd*32 + m (lo short)
  // and z_hi = z_lo + 16 (hi short). So lane (wv,m)'s 4 s-values live at
  // dwords wv*32 + m*2 + {0,1}: fd=0 -> f0(lo)/f1(hi), fd=1 -> f2(lo)/f3(hi).
  {
    const float4* X4 = (const float4*)(X + (size_t)zblk * 64);
    const int rr = lane;
    const int ms = rr & 15;
    const int fd = (rr >> 4) & 1;
    const int ih = rr >> 5;                    // i-half 0/1
    const int zl = wv * 64 + fd * 32 + ms;
    const int zh = zl + 16;
    const int dcol = wv * 32 + ms * 2 + fd;
#pragma unroll
    for (int c4 = 0; c4 < 8; ++c4) {
      const float4 ve = X4[zl * 16 + ih * 8 + c4];
      const float4 vo = X4[zh * 16 + ih * 8 + c4];
      float ae[4], ao[4];
      *(float4*)ae = ve; *(float4*)ao = vo;
      const int i0 = ih * 32 + c4 * 4;
#pragma unroll
      for (int r = 0; r < 4; ++r) {
        const unsigned pk = (unsigned)f2bf_rne(ae[r]) | ((unsigned)f2bf_rne(ao[r]) << 16);
        ldsX[(i0 + r) * XROWD + dcol] = pk;
      }
    }
  }
  // ---- stage B chunk 0 into buf 0 ----
  {
#pragma unroll
    for (int it = 0; it < 4; ++it) {
      const int lin = tid + it * 256;  // 0..1023
      const int row = lin >> 4;        // k 0..63
      const int cc  = lin & 15;        // 0..15
      const uint4 v = *(const uint4*)(Bp + row * 4096 + cc * 8);
      *(uint4*)(&ldsB[0][row * BROWS + cc * 8]) = v;
    }
  }

  // ---- per-lane fp32 j-cache: jv2[f][h*4+e] = {x[z(f,m), h*32+q*8+2e], x[..,+1]} ----
  v2f jv2[4][8];
  {
    const float4* X4g = (const float4*)X;
#pragma unroll
    for (int f = 0; f < 4; ++f) {
      const int zg = zblk + wv * 64 + f * 16 + m;
#pragma unroll
      for (int h = 0; h < 2; ++h) {
        const float4 a = X4g[zg * 16 + h * 8 + q * 2];
        const float4 b = X4g[zg * 16 + h * 8 + q * 2 + 1];
        jv2[f][h * 4 + 0] = v2f{a.x, a.y};
        jv2[f][h * 4 + 1] = v2f{a.z, a.w};
        jv2[f][h * 4 + 2] = v2f{b.x, b.y};
        jv2[f][h * 4 + 3] = v2f{b.z, b.w};
      }
    }
  }

  f32x4 acc[4][4];
#pragma unroll
  for (int f = 0; f < 4; ++f)
#pragma unroll
    for (int g = 0; g < 4; ++g) acc[f][g] = f32x4{0.f, 0.f, 0.f, 0.f};

  __syncthreads();

  for (int c = 0; c < NCHUNK; ++c) {
    // prefetch next B chunk global(L2) -> regs; consumed after the MFMA block
    uint4 pre[4];
    const int cn = (c + 1) & (NCHUNK - 1);
#pragma unroll
    for (int it = 0; it < 4; ++it) {
      const int lin = tid + it * 256;
      const int row = lin >> 4;
      const int cc  = lin & 15;
      pre[it] = *(const uint4*)(Bp + row * 4096 + cn * 128 + cc * 8);
    }

    const unsigned short* Bl = ldsB[c & 1];

#pragma unroll
    for (int il = 0; il < 2; ++il) {
      const int i = c * 2 + il;
      // all 4 s-values (x[z(f,m), i], f=0..3) in one 8B LDS read
      const uint2 sv = *(const uint2*)(ldsX + i * XROWD + wv * 32 + m * 2);
      float sf[4];
      sf[0] = __builtin_bit_cast(float, sv.x << 16);
      sf[1] = __builtin_bit_cast(float, sv.x & 0xffff0000u);
      sf[2] = __builtin_bit_cast(float, sv.y << 16);
      sf[3] = __builtin_bit_cast(float, sv.y & 0xffff0000u);
#pragma unroll
      for (int h = 0; h < 2; ++h) {
        const unsigned short* bb = Bl + m * BROWS + il * 64 + h * 32 + q * 8;
        const short8 b0 = *(const short8*)(bb);
        const short8 b1 = *(const short8*)(bb + 16 * BROWS);
        const short8 b2 = *(const short8*)(bb + 32 * BROWS);
        const short8 b3 = *(const short8*)(bb + 48 * BROWS);
#pragma unroll
        for (int f = 0; f < 4; ++f) {
          const v2f s2 = v2f{sf[f], sf[f]};
          union { unsigned u[4]; short8 v; } A;
#pragma unroll
          for (int e = 0; e < 4; ++e) {
            const v2f pr = s2 * jv2[f][h * 4 + e];   // v_pk_mul_f32
            A.u[e] = pack_bf2(pr[0], pr[1]);
          }
          acc[f][0] = __builtin_amdgcn_mfma_f32_16x16x32_bf16(A.v, b0, acc[f][0], 0, 0, 0);
          acc[f][1] = __builtin_amdgcn_mfma_f32_16x16x32_bf16(A.v, b1, acc[f][1], 0, 0, 0);
          acc[f][2] = __builtin_amdgcn_mfma_f32_16x16x32_bf16(A.v, b2, acc[f][2], 0, 0, 0);
          acc[f][3] = __builtin_amdgcn_mfma_f32_16x16x32_bf16(A.v, b3, acc[f][3], 0, 0, 0);
        }
      }
    }

    // publish prefetched chunk into the other buffer
    {
      unsigned short* dst = ldsB[(c + 1) & 1];
#pragma unroll
      for (int it = 0; it < 4; ++it) {
        const int lin = tid + it * 256;
        const int row = lin >> 4;
        const int cc  = lin & 15;
        *(uint4*)(&dst[row * BROWS + cc * 8]) = pre[it];
      }
    }
    __syncthreads();
  }

  // ---- epilogue: C/D layout col=lane&15 (k), row=q*4+r (z) ----
#pragma unroll
  for (int f = 0; f < 4; ++f) {
    const int zr = zblk + wv * 64 + f * 16 + q * 4;
#pragma unroll
    for (int g = 0; g < 4; ++g)
#pragma unroll
      for (int r = 0; r < 4; ++r)
        out[(size_t)(zr + r) * 64 + g * 16 + m] = acc[f][g][r];
  }
}

extern "C" void kernel_launch(void* const* d_in, const int* in_sizes, int n_in,
                              void* d_out, int out_size, void* d_ws, size_t ws_size,
                              hipStream_t stream) {
  const float* X   = (const float*)d_in[0];   // [131072, 64]
  const float* mix = (const float*)d_in[1];   // [32, 64, 64, 64]
  const float* wgt = (const float*)d_in[2];   // [32]
  float* out = (float*)d_out;                 // [131072, 64]
  unsigned short* Bp = (unsigned short*)d_ws; // 512 KB scratch: M~ bf16 [64][4096]

  prep_kernel<<<1024, 256, 0, stream>>>(mix, wgt, Bp);
  gemm_kernel<<<512, 256, 0, stream>>>(X, Bp, out);
}